// Round 2
// baseline (932.936 us; speedup 1.0000x reference)
//
#include <hip/hip_runtime.h>
#include <cstdint>
#include <cstddef>

// ---- problem dims ----
#define B_ 4
#define T_ 8192
#define W_ 1024
#define L_ 1024
#define H_ 8
#define D_ 128
#define TW_ 4
#define BT_ (B_*T_)        // 32768 rows
#define CHUNK_ 128
#define NCH_ (T_/CHUNK_)   // 64 chunks

typedef __bf16 bf16_t;
typedef __bf16 bf16x8 __attribute__((ext_vector_type(8)));
typedef float  f32x4  __attribute__((ext_vector_type(4)));

__device__ __forceinline__ float  bf2f(bf16_t x){ return (float)x; }
__device__ __forceinline__ bf16_t f2bf(float x){ return (bf16_t)x; }

__device__ __forceinline__ float sigmoidf_(float z){ return 1.0f/(1.0f + __expf(-z)); }
__device__ __forceinline__ float gelu_tanh(float z){
  float g = 0.7978845608028654f*(z + 0.044715f*z*z*z);
  float e = __expf(-2.0f*fabsf(g));
  float th = (1.0f - e)/(1.0f + e);
  th = copysignf(th, g);
  return 0.5f*z*(1.0f + th);
}
__device__ __forceinline__ float softplusf_(float x){
  return (x > 15.0f) ? x : __logf(1.0f + __expf(x));
}

// ---- synchronous staging: 128-row x 32-col bf16 tile into LDS (row-major, no pad)
// 256 threads, each moves 2x 16B. Proven-simple (no async, no addrspace tricks).
__device__ __forceinline__ void stage_tile_sync(const bf16_t* __restrict__ g, int ldg,
                                                bf16_t* __restrict__ lds, int tid){
  #pragma unroll
  for (int it = 0; it < 2; ++it){
    int t = tid + it*256;        // 0..511
    int row = t >> 2;            // 0..127
    int col = (t & 3) * 8;       // 0,8,16,24
    *(bf16x8*)(lds + row*32 + col) = *(const bf16x8*)(g + (size_t)row*ldg + col);
  }
}

// ---- f32 -> bf16 bulk convert (for x) ----
__global__ void __launch_bounds__(256) cvt_kernel(const float* __restrict__ in,
                                                  bf16_t* __restrict__ out, int n8){
  int g = blockIdx.x*256 + threadIdx.x;
  if (g >= n8) return;
  f32x4 a = *(const f32x4*)(in + (size_t)g*8);
  f32x4 b = *(const f32x4*)(in + (size_t)g*8 + 4);
  bf16x8 o;
  #pragma unroll
  for (int e=0;e<4;e++){ o[e] = f2bf(a[e]); o[4+e] = f2bf(b[e]); }
  *(bf16x8*)(out + (size_t)g*8) = o;
}

// ---- batched transpose f32 -> bf16: out[b][c][r] = (bf16)in[b][r][c] ----
__global__ void __launch_bounds__(256) transpose_f2b(const float* __restrict__ in,
                                                     bf16_t* __restrict__ out, int R, int C){
  __shared__ float tile[32][33];
  size_t mb = (size_t)blockIdx.z * R * C;
  int c0 = blockIdx.x*32, r0 = blockIdx.y*32;
  int tx = threadIdx.x, ty = threadIdx.y;
  #pragma unroll
  for (int i = ty; i < 32; i += 8)
    tile[i][tx] = in[mb + (size_t)(r0+i)*C + c0 + tx];
  __syncthreads();
  #pragma unroll
  for (int i = ty; i < 32; i += 8)
    out[mb + (size_t)(c0+i)*R + r0 + tx] = f2bf(tile[tx][i]);
}

// ---- fused K1: Y = gelu(X@Wy + by), U0 = X@Wx + bx.  Xbf:[32768,1024] bf16 ----
__global__ void __launch_bounds__(256) gemm_xw_kernel(
    const bf16_t* __restrict__ X,
    const bf16_t* __restrict__ WyT, const bf16_t* __restrict__ WxT, // [N=1024][K=1024] bf16
    const float* __restrict__ by,  const float* __restrict__ bx,
    bf16_t* __restrict__ Y, bf16_t* __restrict__ U0)
{
  __shared__ __align__(16) bf16_t As[128*32];
  __shared__ __align__(16) bf16_t Bs[128*32];
  const int K = W_;
  int tid = threadIdx.x, wave = tid>>6, lane = tid&63;
  int wm = wave>>1, wn = wave&1, q = lane>>4, ml = lane&15;
  int bm = blockIdx.x, j = blockIdx.y;
  bool isY = (j < 8);
  const bf16_t* WT = isY ? (WyT + (size_t)j*128*K) : (WxT + (size_t)(j-8)*128*K);
  f32x4 acc[4][4] = {};
  for (int k0 = 0; k0 < K; k0 += 32){
    stage_tile_sync(X + (size_t)bm*128*K + k0, K, As, tid);
    stage_tile_sync(WT + k0, K, Bs, tid);
    __syncthreads();
    bf16x8 af[4], bv[4];
    #pragma unroll
    for (int i=0;i<4;i++) af[i] = *(const bf16x8*)(As + (wm*64 + i*16 + ml)*32 + q*8);
    #pragma unroll
    for (int i=0;i<4;i++) bv[i] = *(const bf16x8*)(Bs + (wn*64 + i*16 + ml)*32 + q*8);
    #pragma unroll
    for (int i=0;i<4;i++)
      #pragma unroll
      for (int n=0;n<4;n++)
        acc[i][n] = __builtin_amdgcn_mfma_f32_16x16x32_bf16(af[i], bv[n], acc[i][n], 0,0,0);
    __syncthreads();
  }
  const float* bias = isY ? by : bx;
  bf16_t* Out = isY ? Y : U0;
  int nb = (isY ? j : j-8)*128 + wn*64;
  size_t mbase = (size_t)bm*128 + wm*64;
  #pragma unroll
  for (int n=0;n<4;n++){
    int col = nb + n*16 + ml;
    float bb = bias[col];
    #pragma unroll
    for (int i=0;i<4;i++){
      #pragma unroll
      for (int r=0;r<4;r++){
        size_t row = mbase + i*16 + q*4 + r;
        float v = acc[i][n][r] + bb;
        if (isY) v = gelu_tanh(v);
        Out[row*L_ + col] = f2bf(v);
      }
    }
  }
}

// ---- K2: causal depthwise conv (width 4), f32 weights ----
__global__ void __launch_bounds__(256) conv_kernel(
    const bf16_t* __restrict__ U0, const float* __restrict__ conv_w,
    const float* __restrict__ conv_b, const int* __restrict__ segpos,
    bf16_t* __restrict__ U)
{
  size_t gid = (size_t)blockIdx.x*256 + threadIdx.x;   // BT*L/8 threads
  int lg = (int)(gid & (L_/8 - 1));
  size_t bt = gid >> 7;
  int l = lg*8;
  int t = (int)(bt & (T_-1));
  int pos = segpos[bt];
  float acc[8];
  f32x4 cb0 = *(const f32x4*)(conv_b + l);
  f32x4 cb1 = *(const f32x4*)(conv_b + l + 4);
  #pragma unroll
  for (int e=0;e<4;e++){ acc[e] = cb0[e]; acc[4+e] = cb1[e]; }
  #pragma unroll
  for (int s=0; s<TW_; s++){
    if (pos >= s && t >= s){
      bf16x8 uv = *(const bf16x8*)(U0 + (bt - s)*L_ + l);
      f32x4 w0 = *(const f32x4*)(conv_w + (size_t)(TW_-1-s)*L_ + l);
      f32x4 w1 = *(const f32x4*)(conv_w + (size_t)(TW_-1-s)*L_ + l + 4);
      #pragma unroll
      for (int e=0;e<4;e++){ acc[e] += bf2f(uv[e]) * w0[e]; acc[4+e] += bf2f(uv[4+e]) * w1[e]; }
    }
  }
  bf16x8 o;
  #pragma unroll
  for (int e=0;e<8;e++) o[e] = f2bf(acc[e]);
  *(bf16x8*)(U + bt*L_ + l) = o;
}

// ---- K3: per-head gate GEMMs + RG-LRU prep. Writes XN (aliases U) and L2A. ----
// XN aliasing U is safe: each (bm,h) block reads/writes only its own 128x128 tile,
// and within the block each (row,l) element is read then written by the same thread.
__global__ void __launch_bounds__(256) gate_kernel(
    const bf16_t* __restrict__ U,
    const bf16_t* __restrict__ igTw, const bf16_t* __restrict__ agTw, // [H][e=128][d=128]
    const float* __restrict__ igb,  const float* __restrict__ agb,    // [H*128]
    const float* __restrict__ a_param, const int* __restrict__ segpos,
    bf16_t* __restrict__ XN, bf16_t* __restrict__ L2A)
{
  __shared__ __align__(16) bf16_t As [128*32];
  __shared__ __align__(16) bf16_t Bxs[128*32];
  __shared__ __align__(16) bf16_t Bas[128*32];
  int tid = threadIdx.x, wave = tid>>6, lane = tid&63;
  int wm = wave>>1, wn = wave&1, q = lane>>4, ml = lane&15;
  int bm = blockIdx.x, h = blockIdx.y;
  f32x4 ax[4][4] = {}, aa[4][4] = {};
  for (int k0 = 0; k0 < D_; k0 += 32){
    stage_tile_sync(U + (size_t)bm*128*L_ + h*D_ + k0, L_, As, tid);
    stage_tile_sync(igTw + (size_t)h*D_*D_ + k0, D_, Bxs, tid);
    stage_tile_sync(agTw + (size_t)h*D_*D_ + k0, D_, Bas, tid);
    __syncthreads();
    bf16x8 af[4], bx_[4], ba_[4];
    #pragma unroll
    for (int i=0;i<4;i++) af[i]  = *(const bf16x8*)(As  + (wm*64 + i*16 + ml)*32 + q*8);
    #pragma unroll
    for (int i=0;i<4;i++) bx_[i] = *(const bf16x8*)(Bxs + (wn*64 + i*16 + ml)*32 + q*8);
    #pragma unroll
    for (int i=0;i<4;i++) ba_[i] = *(const bf16x8*)(Bas + (wn*64 + i*16 + ml)*32 + q*8);
    #pragma unroll
    for (int i=0;i<4;i++)
      #pragma unroll
      for (int n=0;n<4;n++){
        ax[i][n] = __builtin_amdgcn_mfma_f32_16x16x32_bf16(af[i], bx_[n], ax[i][n], 0,0,0);
        aa[i][n] = __builtin_amdgcn_mfma_f32_16x16x32_bf16(af[i], ba_[n], aa[i][n], 0,0,0);
      }
    __syncthreads();
  }
  size_t mbase = (size_t)bm*128 + wm*64;
  #pragma unroll
  for (int n=0;n<4;n++){
    int e = wn*64 + n*16 + ml;
    int l = h*D_ + e;
    float bbx = igb[l];
    float bba = agb[l];
    float spa = softplusf_(a_param[l]);   // softplus(a_param) >= 0
    #pragma unroll
    for (int i=0;i<4;i++){
      #pragma unroll
      for (int r=0;r<4;r++){
        size_t row = mbase + i*16 + q*4 + r;
        int pos = segpos[row];
        float uval = bf2f(U[row*L_ + l]);
        float gx = sigmoidf_(ax[i][n][r] + bbx);
        float ga = sigmoidf_(aa[i][n][r] + bba);
        float l2a = -8.0f * ga * spa * 1.4426950408889634f;  // log2(a)
        bool reset = (pos == 0);
        float mult = reset ? 1.0f : sqrtf(fmaxf(0.0f, 1.0f - exp2f(2.0f*l2a)));
        XN [row*L_ + l] = f2bf(uval * gx * mult);
        L2A[row*L_ + l] = f2bf(reset ? -1e30f : l2a);
      }
    }
  }
}

// ---- K4..K6: chunked linear scan h_t = a_t h_{t-1} + xn_t ----
__global__ void __launch_bounds__(256) scan1_kernel(const bf16_t* __restrict__ L2A,
    const bf16_t* __restrict__ XN, float* __restrict__ Aarr, float* __restrict__ Barr)
{
  int l = blockIdx.x*256 + threadIdx.x;
  int c = blockIdx.y, b = blockIdx.z;
  size_t base = ((size_t)b*T_ + (size_t)c*CHUNK_)*L_ + l;
  float suml = 0.0f, brun = 0.0f;
  for (int t = 0; t < CHUNK_; ++t){
    float la = bf2f(L2A[base + (size_t)t*L_]);
    float xv = bf2f(XN [base + (size_t)t*L_]);
    suml += la;
    brun = exp2f(la)*brun + xv;
  }
  size_t ci = ((size_t)b*NCH_ + c)*L_ + l;
  Aarr[ci] = exp2f(suml);
  Barr[ci] = brun;
}

__global__ void __launch_bounds__(256) scan2_kernel(const float* __restrict__ Aarr,
    const float* __restrict__ Barr, float* __restrict__ Carr)
{
  int l = blockIdx.x*256 + threadIdx.x;
  int b = blockIdx.y;
  float h = 0.0f;
  for (int c = 0; c < NCH_; ++c){
    size_t ci = ((size_t)b*NCH_ + c)*L_ + l;
    Carr[ci] = h;
    h = Aarr[ci]*h + Barr[ci];
  }
}

__global__ void __launch_bounds__(256) scan3_kernel(const bf16_t* __restrict__ L2A,
    const bf16_t* __restrict__ XN, const bf16_t* __restrict__ Y,
    const float* __restrict__ Carr, bf16_t* __restrict__ HY)
{
  int l = blockIdx.x*256 + threadIdx.x;
  int c = blockIdx.y, b = blockIdx.z;
  size_t base = ((size_t)b*T_ + (size_t)c*CHUNK_)*L_ + l;
  float h = Carr[((size_t)b*NCH_ + c)*L_ + l];
  for (int t = 0; t < CHUNK_; ++t){
    float la = bf2f(L2A[base + (size_t)t*L_]);
    float xv = bf2f(XN [base + (size_t)t*L_]);
    h = exp2f(la)*h + xv;
    float yv = bf2f(Y[base + (size_t)t*L_]);
    HY[base + (size_t)t*L_] = f2bf(h*yv);
  }
}

// ---- K7: out = HY @ Wout + bout (f32 output) ----
__global__ void __launch_bounds__(256) gemm_out_kernel(
    const bf16_t* __restrict__ A_, const bf16_t* __restrict__ WoT, // [N=1024][K=1024]
    const float* __restrict__ bo, float* __restrict__ Out)
{
  __shared__ __align__(16) bf16_t As[128*32];
  __shared__ __align__(16) bf16_t Bs[128*32];
  const int K = L_;
  int tid = threadIdx.x, wave = tid>>6, lane = tid&63;
  int wm = wave>>1, wn = wave&1, q = lane>>4, ml = lane&15;
  int bm = blockIdx.x, j = blockIdx.y;
  f32x4 acc[4][4] = {};
  for (int k0 = 0; k0 < K; k0 += 32){
    stage_tile_sync(A_ + (size_t)bm*128*K + k0, K, As, tid);
    stage_tile_sync(WoT + (size_t)j*128*K + k0, K, Bs, tid);
    __syncthreads();
    bf16x8 af[4], bv[4];
    #pragma unroll
    for (int i=0;i<4;i++) af[i] = *(const bf16x8*)(As + (wm*64 + i*16 + ml)*32 + q*8);
    #pragma unroll
    for (int i=0;i<4;i++) bv[i] = *(const bf16x8*)(Bs + (wn*64 + i*16 + ml)*32 + q*8);
    #pragma unroll
    for (int i=0;i<4;i++)
      #pragma unroll
      for (int n=0;n<4;n++)
        acc[i][n] = __builtin_amdgcn_mfma_f32_16x16x32_bf16(af[i], bv[n], acc[i][n], 0,0,0);
    __syncthreads();
  }
  int nb = j*128 + wn*64;
  size_t mbase = (size_t)bm*128 + wm*64;
  #pragma unroll
  for (int n=0;n<4;n++){
    int col = nb + n*16 + ml;
    float bb = bo[col];
    #pragma unroll
    for (int i=0;i<4;i++){
      #pragma unroll
      for (int r=0;r<4;r++){
        size_t row = mbase + i*16 + q*4 + r;
        Out[row*W_ + col] = acc[i][n][r] + bb;
      }
    }
  }
}

extern "C" void kernel_launch(void* const* d_in, const int* in_sizes, int n_in,
                              void* d_out, int out_size, void* d_ws, size_t ws_size,
                              hipStream_t stream)
{
  (void)in_sizes; (void)n_in; (void)out_size;
  const float* x      = (const float*)d_in[0];
  const int*   segpos = (const int*)  d_in[1];
  const float* Wy     = (const float*)d_in[2];
  const float* by     = (const float*)d_in[3];
  const float* Wx     = (const float*)d_in[4];
  const float* bx     = (const float*)d_in[5];
  const float* conv_w = (const float*)d_in[6];
  const float* conv_b = (const float*)d_in[7];
  const float* a_par  = (const float*)d_in[8];
  const float* igw    = (const float*)d_in[9];
  const float* igb    = (const float*)d_in[10];
  const float* agw    = (const float*)d_in[11];
  const float* agb    = (const float*)d_in[12];
  const float* Wout   = (const float*)d_in[13];
  const float* bout   = (const float*)d_in[14];
  float* out = (float*)d_out;

  char* ws = (char*)d_ws;
  size_t off = 0;
  auto alloc = [&](size_t bytes)->void*{ void* p = ws + off; off += (bytes + 255) & ~(size_t)255; return p; };
  bf16_t* Xbf  = (bf16_t*)alloc((size_t)BT_*W_*2);      // x in bf16; dead after gemm_xw
  bf16_t* WyT  = (bf16_t*)alloc((size_t)W_*L_*2);
  bf16_t* WxT  = (bf16_t*)alloc((size_t)W_*L_*2);
  bf16_t* WoT  = (bf16_t*)alloc((size_t)L_*W_*2);
  bf16_t* igTw = (bf16_t*)alloc((size_t)H_*D_*D_*2);
  bf16_t* agTw = (bf16_t*)alloc((size_t)H_*D_*D_*2);
  bf16_t* Y    = (bf16_t*)alloc((size_t)BT_*L_*2);
  bf16_t* U0   = (bf16_t*)alloc((size_t)BT_*L_*2);      // reused as HY after scan3
  bf16_t* U    = (bf16_t*)alloc((size_t)BT_*L_*2);      // reused as XN by gate epilogue
  float*  Aarr = (float*) alloc((size_t)B_*NCH_*L_*4);
  float*  Barr = (float*) alloc((size_t)B_*NCH_*L_*4);
  float*  Carr = (float*) alloc((size_t)B_*NCH_*L_*4);
  if (ws_size < off) return;  // insufficient workspace: output stays zero (diagnosable)

  bf16_t* L2A = Xbf;   // alias: Xbf dead once gemm_xw completes, before gate_kernel
  bf16_t* HY  = U0;
  bf16_t* XN  = U;

  cvt_kernel<<<dim3(BT_*W_/8/256), 256, 0, stream>>>(x, Xbf, BT_*W_/8);

  dim3 tb(32, 8);
  transpose_f2b<<<dim3(32,32,1), tb, 0, stream>>>(Wy,   WyT, 1024, 1024);
  transpose_f2b<<<dim3(32,32,1), tb, 0, stream>>>(Wx,   WxT, 1024, 1024);
  transpose_f2b<<<dim3(32,32,1), tb, 0, stream>>>(Wout, WoT, 1024, 1024);
  transpose_f2b<<<dim3(4,4,H_),  tb, 0, stream>>>(igw,  igTw, 128, 128);
  transpose_f2b<<<dim3(4,4,H_),  tb, 0, stream>>>(agw,  agTw, 128, 128);

  gemm_xw_kernel<<<dim3(BT_/128, 16), 256, 0, stream>>>(Xbf, WyT, WxT, by, bx, Y, U0);
  conv_kernel<<<dim3(BT_*L_/8/256), 256, 0, stream>>>(U0, conv_w, conv_b, segpos, U);
  gate_kernel<<<dim3(BT_/128, H_), 256, 0, stream>>>(U, igTw, agTw, igb, agb, a_par, segpos, XN, L2A);
  scan1_kernel<<<dim3(L_/256, NCH_, B_), 256, 0, stream>>>(L2A, XN, Aarr, Barr);
  scan2_kernel<<<dim3(L_/256, B_), 256, 0, stream>>>(Aarr, Barr, Carr);
  scan3_kernel<<<dim3(L_/256, NCH_, B_), 256, 0, stream>>>(L2A, XN, Y, Carr, HY);
  gemm_out_kernel<<<dim3(BT_/128, 8), 256, 0, stream>>>(HY, WoT, bout, out);
}

// Round 3
// 895.887 us; speedup vs baseline: 1.0414x; 1.0414x over previous
//
#include <hip/hip_runtime.h>
#include <cstdint>
#include <cstddef>

// ---- problem dims ----
#define B_ 4
#define T_ 8192
#define W_ 1024
#define L_ 1024
#define H_ 8
#define D_ 128
#define TW_ 4
#define BT_ (B_*T_)        // 32768 rows
#define CHUNK_ 128
#define NCH_ (T_/CHUNK_)   // 64 chunks

typedef __bf16 bf16_t;
typedef __bf16 bf16x8 __attribute__((ext_vector_type(8)));
typedef float  f32x4  __attribute__((ext_vector_type(4)));

__device__ __forceinline__ float  bf2f(bf16_t x){ return (float)x; }
__device__ __forceinline__ bf16_t f2bf(float x){ return (bf16_t)x; }

__device__ __forceinline__ float sigmoidf_(float z){ return 1.0f/(1.0f + __expf(-z)); }
__device__ __forceinline__ float gelu_tanh(float z){
  float g = 0.7978845608028654f*(z + 0.044715f*z*z*z);
  float e = __expf(-2.0f*fabsf(g));
  float th = (1.0f - e)/(1.0f + e);
  th = copysignf(th, g);
  return 0.5f*z*(1.0f + th);
}
__device__ __forceinline__ float softplusf_(float x){
  return (x > 15.0f) ? x : __logf(1.0f + __expf(x));
}

// ---- async global->LDS staging: 128-row x 32-col bf16 tile, row-major, no pad ----
// LDS dest for global_load_lds is wave-uniform base + lane*16B; our layout is exactly
// that (chunk*1024B + lane*16B == row-major [128][32] with row=chunk*16+lane/4,
// col=(lane&3)*8). Verified pattern from the m97 ladder step.
__device__ __forceinline__ void stage16(const bf16_t* g, bf16_t* l){
  __builtin_amdgcn_global_load_lds((const __attribute__((address_space(1))) void*)g,
                                   (__attribute__((address_space(3))) void*)l, 16, 0, 0);
}
__device__ __forceinline__ void stage_tile(const bf16_t* __restrict__ gbase, int ldg,
                                           bf16_t* lds, int wave, int lane){
  #pragma unroll
  for (int c2 = 0; c2 < 2; ++c2){
    int chunk = wave*2 + c2;
    int row = chunk*16 + (lane >> 2);
    int col = (lane & 3)*8;
    stage16(gbase + (size_t)row*ldg + col, lds + chunk*512 + lane*8);
  }
}

// ---- f32 -> bf16 bulk convert (for x) ----
__global__ void __launch_bounds__(256) cvt_kernel(const float* __restrict__ in,
                                                  bf16_t* __restrict__ out, int n8){
  int g = blockIdx.x*256 + threadIdx.x;
  if (g >= n8) return;
  f32x4 a = *(const f32x4*)(in + (size_t)g*8);
  f32x4 b = *(const f32x4*)(in + (size_t)g*8 + 4);
  bf16x8 o;
  #pragma unroll
  for (int e=0;e<4;e++){ o[e] = f2bf(a[e]); o[4+e] = f2bf(b[e]); }
  *(bf16x8*)(out + (size_t)g*8) = o;
}

// ---- batched transpose f32 -> bf16: out[b][c][r] = (bf16)in[b][r][c] ----
__global__ void __launch_bounds__(256) transpose_f2b(const float* __restrict__ in,
                                                     bf16_t* __restrict__ out, int R, int C){
  __shared__ float tile[32][33];
  size_t mb = (size_t)blockIdx.z * R * C;
  int c0 = blockIdx.x*32, r0 = blockIdx.y*32;
  int tx = threadIdx.x, ty = threadIdx.y;
  #pragma unroll
  for (int i = ty; i < 32; i += 8)
    tile[i][tx] = in[mb + (size_t)(r0+i)*C + c0 + tx];
  __syncthreads();
  #pragma unroll
  for (int i = ty; i < 32; i += 8)
    out[mb + (size_t)(c0+i)*R + r0 + tx] = f2bf(tile[tx][i]);
}

// ---- fused K1: Y = gelu(X@Wy + by), U0 = X@Wx + bx.  Xbf:[32768,1024] bf16 ----
__global__ void __launch_bounds__(256) gemm_xw_kernel(
    const bf16_t* __restrict__ X,
    const bf16_t* __restrict__ WyT, const bf16_t* __restrict__ WxT, // [N=1024][K=1024] bf16
    const float* __restrict__ by,  const float* __restrict__ bx,
    bf16_t* __restrict__ Y, bf16_t* __restrict__ U0)
{
  __shared__ __align__(16) bf16_t As[128*32];
  __shared__ __align__(16) bf16_t Bs[128*32];
  const int K = W_;
  int tid = threadIdx.x, wave = tid>>6, lane = tid&63;
  int wm = wave>>1, wn = wave&1, q = lane>>4, ml = lane&15;
  int bm = blockIdx.x, j = blockIdx.y;
  bool isY = (j < 8);
  const bf16_t* WT = isY ? (WyT + (size_t)j*128*K) : (WxT + (size_t)(j-8)*128*K);
  f32x4 acc[4][4] = {};
  for (int k0 = 0; k0 < K; k0 += 32){
    stage_tile(X + (size_t)bm*128*K + k0, K, As, wave, lane);
    stage_tile(WT + k0, K, Bs, wave, lane);
    __syncthreads();
    bf16x8 af[4], bv[4];
    #pragma unroll
    for (int i=0;i<4;i++) af[i] = *(const bf16x8*)(As + (wm*64 + i*16 + ml)*32 + q*8);
    #pragma unroll
    for (int i=0;i<4;i++) bv[i] = *(const bf16x8*)(Bs + (wn*64 + i*16 + ml)*32 + q*8);
    #pragma unroll
    for (int i=0;i<4;i++)
      #pragma unroll
      for (int n=0;n<4;n++)
        acc[i][n] = __builtin_amdgcn_mfma_f32_16x16x32_bf16(af[i], bv[n], acc[i][n], 0,0,0);
    __syncthreads();
  }
  const float* bias = isY ? by : bx;
  bf16_t* Out = isY ? Y : U0;
  int nb = (isY ? j : j-8)*128 + wn*64;
  size_t mbase = (size_t)bm*128 + wm*64;
  #pragma unroll
  for (int n=0;n<4;n++){
    int col = nb + n*16 + ml;
    float bb = bias[col];
    #pragma unroll
    for (int i=0;i<4;i++){
      #pragma unroll
      for (int r=0;r<4;r++){
        size_t row = mbase + i*16 + q*4 + r;
        float v = acc[i][n][r] + bb;
        if (isY) v = gelu_tanh(v);
        Out[row*L_ + col] = f2bf(v);
      }
    }
  }
}

// ---- K2: causal depthwise conv (width 4), f32 weights ----
__global__ void __launch_bounds__(256) conv_kernel(
    const bf16_t* __restrict__ U0, const float* __restrict__ conv_w,
    const float* __restrict__ conv_b, const int* __restrict__ segpos,
    bf16_t* __restrict__ U)
{
  size_t gid = (size_t)blockIdx.x*256 + threadIdx.x;   // BT*L/8 threads
  int lg = (int)(gid & (L_/8 - 1));
  size_t bt = gid >> 7;
  int l = lg*8;
  int t = (int)(bt & (T_-1));
  int pos = segpos[bt];
  float acc[8];
  f32x4 cb0 = *(const f32x4*)(conv_b + l);
  f32x4 cb1 = *(const f32x4*)(conv_b + l + 4);
  #pragma unroll
  for (int e=0;e<4;e++){ acc[e] = cb0[e]; acc[4+e] = cb1[e]; }
  #pragma unroll
  for (int s=0; s<TW_; s++){
    if (pos >= s && t >= s){
      bf16x8 uv = *(const bf16x8*)(U0 + (bt - s)*L_ + l);
      f32x4 w0 = *(const f32x4*)(conv_w + (size_t)(TW_-1-s)*L_ + l);
      f32x4 w1 = *(const f32x4*)(conv_w + (size_t)(TW_-1-s)*L_ + l + 4);
      #pragma unroll
      for (int e=0;e<4;e++){ acc[e] += bf2f(uv[e]) * w0[e]; acc[4+e] += bf2f(uv[4+e]) * w1[e]; }
    }
  }
  bf16x8 o;
  #pragma unroll
  for (int e=0;e<8;e++) o[e] = f2bf(acc[e]);
  *(bf16x8*)(U + bt*L_ + l) = o;
}

// ---- K3: per-head gate GEMMs + RG-LRU prep. Writes XN (aliases U) and L2A. ----
__global__ void __launch_bounds__(256) gate_kernel(
    const bf16_t* __restrict__ U,
    const bf16_t* __restrict__ igTw, const bf16_t* __restrict__ agTw, // [H][e=128][d=128]
    const float* __restrict__ igb,  const float* __restrict__ agb,    // [H*128]
    const float* __restrict__ a_param, const int* __restrict__ segpos,
    bf16_t* __restrict__ XN, bf16_t* __restrict__ L2A)
{
  __shared__ __align__(16) bf16_t As [128*32];
  __shared__ __align__(16) bf16_t Bxs[128*32];
  __shared__ __align__(16) bf16_t Bas[128*32];
  int tid = threadIdx.x, wave = tid>>6, lane = tid&63;
  int wm = wave>>1, wn = wave&1, q = lane>>4, ml = lane&15;
  int bm = blockIdx.x, h = blockIdx.y;
  f32x4 ax[4][4] = {}, aa[4][4] = {};
  for (int k0 = 0; k0 < D_; k0 += 32){
    stage_tile(U + (size_t)bm*128*L_ + h*D_ + k0, L_, As, wave, lane);
    stage_tile(igTw + (size_t)h*D_*D_ + k0, D_, Bxs, wave, lane);
    stage_tile(agTw + (size_t)h*D_*D_ + k0, D_, Bas, wave, lane);
    __syncthreads();
    bf16x8 af[4], bx_[4], ba_[4];
    #pragma unroll
    for (int i=0;i<4;i++) af[i]  = *(const bf16x8*)(As  + (wm*64 + i*16 + ml)*32 + q*8);
    #pragma unroll
    for (int i=0;i<4;i++) bx_[i] = *(const bf16x8*)(Bxs + (wn*64 + i*16 + ml)*32 + q*8);
    #pragma unroll
    for (int i=0;i<4;i++) ba_[i] = *(const bf16x8*)(Bas + (wn*64 + i*16 + ml)*32 + q*8);
    #pragma unroll
    for (int i=0;i<4;i++)
      #pragma unroll
      for (int n=0;n<4;n++){
        ax[i][n] = __builtin_amdgcn_mfma_f32_16x16x32_bf16(af[i], bx_[n], ax[i][n], 0,0,0);
        aa[i][n] = __builtin_amdgcn_mfma_f32_16x16x32_bf16(af[i], ba_[n], aa[i][n], 0,0,0);
      }
    __syncthreads();
  }
  size_t mbase = (size_t)bm*128 + wm*64;
  #pragma unroll
  for (int n=0;n<4;n++){
    int e = wn*64 + n*16 + ml;
    int l = h*D_ + e;
    float bbx = igb[l];
    float bba = agb[l];
    float spa = softplusf_(a_param[l]);   // softplus(a_param) >= 0
    #pragma unroll
    for (int i=0;i<4;i++){
      #pragma unroll
      for (int r=0;r<4;r++){
        size_t row = mbase + i*16 + q*4 + r;
        int pos = segpos[row];
        float uval = bf2f(U[row*L_ + l]);
        float gx = sigmoidf_(ax[i][n][r] + bbx);
        float ga = sigmoidf_(aa[i][n][r] + bba);
        float l2a = -8.0f * ga * spa * 1.4426950408889634f;  // log2(a)
        bool reset = (pos == 0);
        float mult = reset ? 1.0f : sqrtf(fmaxf(0.0f, 1.0f - exp2f(2.0f*l2a)));
        XN [row*L_ + l] = f2bf(uval * gx * mult);
        L2A[row*L_ + l] = f2bf(reset ? -1e30f : l2a);
      }
    }
  }
}

// ---- K4..K6: chunked linear scan h_t = a_t h_{t-1} + xn_t ----
__global__ void __launch_bounds__(256) scan1_kernel(const bf16_t* __restrict__ L2A,
    const bf16_t* __restrict__ XN, float* __restrict__ Aarr, float* __restrict__ Barr)
{
  int l = blockIdx.x*256 + threadIdx.x;
  int c = blockIdx.y, b = blockIdx.z;
  size_t base = ((size_t)b*T_ + (size_t)c*CHUNK_)*L_ + l;
  float suml = 0.0f, brun = 0.0f;
  for (int t = 0; t < CHUNK_; ++t){
    float la = bf2f(L2A[base + (size_t)t*L_]);
    float xv = bf2f(XN [base + (size_t)t*L_]);
    suml += la;
    brun = exp2f(la)*brun + xv;
  }
  size_t ci = ((size_t)b*NCH_ + c)*L_ + l;
  Aarr[ci] = exp2f(suml);
  Barr[ci] = brun;
}

__global__ void __launch_bounds__(256) scan2_kernel(const float* __restrict__ Aarr,
    const float* __restrict__ Barr, float* __restrict__ Carr)
{
  int l = blockIdx.x*256 + threadIdx.x;
  int b = blockIdx.y;
  float h = 0.0f;
  for (int c = 0; c < NCH_; ++c){
    size_t ci = ((size_t)b*NCH_ + c)*L_ + l;
    Carr[ci] = h;
    h = Aarr[ci]*h + Barr[ci];
  }
}

__global__ void __launch_bounds__(256) scan3_kernel(const bf16_t* __restrict__ L2A,
    const bf16_t* __restrict__ XN, const bf16_t* __restrict__ Y,
    const float* __restrict__ Carr, bf16_t* __restrict__ HY)
{
  int l = blockIdx.x*256 + threadIdx.x;
  int c = blockIdx.y, b = blockIdx.z;
  size_t base = ((size_t)b*T_ + (size_t)c*CHUNK_)*L_ + l;
  float h = Carr[((size_t)b*NCH_ + c)*L_ + l];
  for (int t = 0; t < CHUNK_; ++t){
    float la = bf2f(L2A[base + (size_t)t*L_]);
    float xv = bf2f(XN [base + (size_t)t*L_]);
    h = exp2f(la)*h + xv;
    float yv = bf2f(Y[base + (size_t)t*L_]);
    HY[base + (size_t)t*L_] = f2bf(h*yv);
  }
}

// ---- K7: out = HY @ Wout + bout (f32 output) ----
__global__ void __launch_bounds__(256) gemm_out_kernel(
    const bf16_t* __restrict__ A_, const bf16_t* __restrict__ WoT, // [N=1024][K=1024]
    const float* __restrict__ bo, float* __restrict__ Out)
{
  __shared__ __align__(16) bf16_t As[128*32];
  __shared__ __align__(16) bf16_t Bs[128*32];
  const int K = L_;
  int tid = threadIdx.x, wave = tid>>6, lane = tid&63;
  int wm = wave>>1, wn = wave&1, q = lane>>4, ml = lane&15;
  int bm = blockIdx.x, j = blockIdx.y;
  f32x4 acc[4][4] = {};
  for (int k0 = 0; k0 < K; k0 += 32){
    stage_tile(A_ + (size_t)bm*128*K + k0, K, As, wave, lane);
    stage_tile(WoT + (size_t)j*128*K + k0, K, Bs, wave, lane);
    __syncthreads();
    bf16x8 af[4], bv[4];
    #pragma unroll
    for (int i=0;i<4;i++) af[i] = *(const bf16x8*)(As + (wm*64 + i*16 + ml)*32 + q*8);
    #pragma unroll
    for (int i=0;i<4;i++) bv[i] = *(const bf16x8*)(Bs + (wn*64 + i*16 + ml)*32 + q*8);
    #pragma unroll
    for (int i=0;i<4;i++)
      #pragma unroll
      for (int n=0;n<4;n++)
        acc[i][n] = __builtin_amdgcn_mfma_f32_16x16x32_bf16(af[i], bv[n], acc[i][n], 0,0,0);
    __syncthreads();
  }
  int nb = j*128 + wn*64;
  size_t mbase = (size_t)bm*128 + wm*64;
  #pragma unroll
  for (int n=0;n<4;n++){
    int col = nb + n*16 + ml;
    float bb = bo[col];
    #pragma unroll
    for (int i=0;i<4;i++){
      #pragma unroll
      for (int r=0;r<4;r++){
        size_t row = mbase + i*16 + q*4 + r;
        Out[row*W_ + col] = acc[i][n][r] + bb;
      }
    }
  }
}

extern "C" void kernel_launch(void* const* d_in, const int* in_sizes, int n_in,
                              void* d_out, int out_size, void* d_ws, size_t ws_size,
                              hipStream_t stream)
{
  (void)in_sizes; (void)n_in; (void)out_size;
  const float* x      = (const float*)d_in[0];
  const int*   segpos = (const int*)  d_in[1];
  const float* Wy     = (const float*)d_in[2];
  const float* by     = (const float*)d_in[3];
  const float* Wx     = (const float*)d_in[4];
  const float* bx     = (const float*)d_in[5];
  const float* conv_w = (const float*)d_in[6];
  const float* conv_b = (const float*)d_in[7];
  const float* a_par  = (const float*)d_in[8];
  const float* igw    = (const float*)d_in[9];
  const float* igb    = (const float*)d_in[10];
  const float* agw    = (const float*)d_in[11];
  const float* agb    = (const float*)d_in[12];
  const float* Wout   = (const float*)d_in[13];
  const float* bout   = (const float*)d_in[14];
  float* out = (float*)d_out;

  char* ws = (char*)d_ws;
  size_t off = 0;
  auto alloc = [&](size_t bytes)->void*{ void* p = ws + off; off += (bytes + 255) & ~(size_t)255; return p; };
  bf16_t* Xbf  = (bf16_t*)alloc((size_t)BT_*W_*2);      // x in bf16; dead after gemm_xw
  bf16_t* WyT  = (bf16_t*)alloc((size_t)W_*L_*2);
  bf16_t* WxT  = (bf16_t*)alloc((size_t)W_*L_*2);
  bf16_t* WoT  = (bf16_t*)alloc((size_t)L_*W_*2);
  bf16_t* igTw = (bf16_t*)alloc((size_t)H_*D_*D_*2);
  bf16_t* agTw = (bf16_t*)alloc((size_t)H_*D_*D_*2);
  bf16_t* Y    = (bf16_t*)alloc((size_t)BT_*L_*2);
  bf16_t* U0   = (bf16_t*)alloc((size_t)BT_*L_*2);      // reused as HY after scan3
  bf16_t* U    = (bf16_t*)alloc((size_t)BT_*L_*2);      // reused as XN by gate epilogue
  float*  Aarr = (float*) alloc((size_t)B_*NCH_*L_*4);
  float*  Barr = (float*) alloc((size_t)B_*NCH_*L_*4);
  float*  Carr = (float*) alloc((size_t)B_*NCH_*L_*4);
  if (ws_size < off) return;  // insufficient workspace: output stays zero (diagnosable)

  bf16_t* L2A = Xbf;   // alias: Xbf dead once gemm_xw completes, before gate_kernel
  bf16_t* HY  = U0;
  bf16_t* XN  = U;

  cvt_kernel<<<dim3(BT_*W_/8/256), 256, 0, stream>>>(x, Xbf, BT_*W_/8);

  dim3 tb(32, 8);
  transpose_f2b<<<dim3(32,32,1), tb, 0, stream>>>(Wy,   WyT, 1024, 1024);
  transpose_f2b<<<dim3(32,32,1), tb, 0, stream>>>(Wx,   WxT, 1024, 1024);
  transpose_f2b<<<dim3(32,32,1), tb, 0, stream>>>(Wout, WoT, 1024, 1024);
  transpose_f2b<<<dim3(4,4,H_),  tb, 0, stream>>>(igw,  igTw, 128, 128);
  transpose_f2b<<<dim3(4,4,H_),  tb, 0, stream>>>(agw,  agTw, 128, 128);

  gemm_xw_kernel<<<dim3(BT_/128, 16), 256, 0, stream>>>(Xbf, WyT, WxT, by, bx, Y, U0);
  conv_kernel<<<dim3(BT_*L_/8/256), 256, 0, stream>>>(U0, conv_w, conv_b, segpos, U);
  gate_kernel<<<dim3(BT_/128, H_), 256, 0, stream>>>(U, igTw, agTw, igb, agb, a_par, segpos, XN, L2A);
  scan1_kernel<<<dim3(L_/256, NCH_, B_), 256, 0, stream>>>(L2A, XN, Aarr, Barr);
  scan2_kernel<<<dim3(L_/256, B_), 256, 0, stream>>>(Aarr, Barr, Carr);
  scan3_kernel<<<dim3(L_/256, NCH_, B_), 256, 0, stream>>>(L2A, XN, Y, Carr, HY);
  gemm_out_kernel<<<dim3(BT_/128, 8), 256, 0, stream>>>(HY, WoT, bout, out);
}

// Round 4
// 816.321 us; speedup vs baseline: 1.1429x; 1.0975x over previous
//
#include <hip/hip_runtime.h>
#include <cstdint>
#include <cstddef>

// ---- problem dims ----
#define B_ 4
#define T_ 8192
#define W_ 1024
#define L_ 1024
#define H_ 8
#define D_ 128
#define TW_ 4
#define BT_ (B_*T_)        // 32768 rows
#define CHUNK_ 128
#define NCH_ (T_/CHUNK_)   // 64 chunks

typedef __bf16 bf16_t;
typedef __bf16 bf16x8 __attribute__((ext_vector_type(8)));
typedef float  f32x4  __attribute__((ext_vector_type(4)));

__device__ __forceinline__ float  bf2f(bf16_t x){ return (float)x; }
__device__ __forceinline__ bf16_t f2bf(float x){ return (bf16_t)x; }

__device__ __forceinline__ float sigmoidf_(float z){ return 1.0f/(1.0f + __expf(-z)); }
__device__ __forceinline__ float gelu_tanh(float z){
  float g = 0.7978845608028654f*(z + 0.044715f*z*z*z);
  float e = __expf(-2.0f*fabsf(g));
  float th = (1.0f - e)/(1.0f + e);
  th = copysignf(th, g);
  return 0.5f*z*(1.0f + th);
}
__device__ __forceinline__ float softplusf_(float x){
  return (x > 15.0f) ? x : __logf(1.0f + __expf(x));
}

// ---- async global->LDS staging: 128-row x 32-col bf16 tile, row-major, no pad ----
__device__ __forceinline__ void stage16(const bf16_t* g, bf16_t* l){
  __builtin_amdgcn_global_load_lds((const __attribute__((address_space(1))) void*)g,
                                   (__attribute__((address_space(3))) void*)l, 16, 0, 0);
}
__device__ __forceinline__ void stage_tile(const bf16_t* __restrict__ gbase, int ldg,
                                           bf16_t* lds, int wave, int lane){
  #pragma unroll
  for (int c2 = 0; c2 < 2; ++c2){
    int chunk = wave*2 + c2;
    int row = chunk*16 + (lane >> 2);
    int col = (lane & 3)*8;
    stage16(gbase + (size_t)row*ldg + col, lds + chunk*512 + lane*8);
  }
}

// ---- f32 -> bf16 bulk convert (for x) ----
__global__ void __launch_bounds__(256) cvt_kernel(const float* __restrict__ in,
                                                  bf16_t* __restrict__ out, int n8){
  int g = blockIdx.x*256 + threadIdx.x;
  if (g >= n8) return;
  f32x4 a = *(const f32x4*)(in + (size_t)g*8);
  f32x4 b = *(const f32x4*)(in + (size_t)g*8 + 4);
  bf16x8 o;
  #pragma unroll
  for (int e=0;e<4;e++){ o[e] = f2bf(a[e]); o[4+e] = f2bf(b[e]); }
  *(bf16x8*)(out + (size_t)g*8) = o;
}

// ---- batched transpose f32 -> bf16: out[b][c][r] = (bf16)in[b][r][c] ----
__global__ void __launch_bounds__(256) transpose_f2b(const float* __restrict__ in,
                                                     bf16_t* __restrict__ out, int R, int C){
  __shared__ float tile[32][33];
  size_t mb = (size_t)blockIdx.z * R * C;
  int c0 = blockIdx.x*32, r0 = blockIdx.y*32;
  int tx = threadIdx.x, ty = threadIdx.y;
  #pragma unroll
  for (int i = ty; i < 32; i += 8)
    tile[i][tx] = in[mb + (size_t)(r0+i)*C + c0 + tx];
  __syncthreads();
  #pragma unroll
  for (int i = ty; i < 32; i += 8)
    out[mb + (size_t)(c0+i)*R + r0 + tx] = f2bf(tile[tx][i]);
}

// ---- fused K1: Y = gelu(X@Wy + by), U0 = X@Wx + bx. One block does BOTH
//      surfaces for its 128-col slice: A-tile staged once feeds 32 MFMA/wave/iter.
__global__ void __launch_bounds__(256,2) gemm_xw_kernel(
    const bf16_t* __restrict__ X,
    const bf16_t* __restrict__ WyT, const bf16_t* __restrict__ WxT, // [N=1024][K=1024] bf16
    const float* __restrict__ by,  const float* __restrict__ bx,
    bf16_t* __restrict__ Y, bf16_t* __restrict__ U0)
{
  __shared__ __align__(16) bf16_t As [128*32];
  __shared__ __align__(16) bf16_t Bys[128*32];
  __shared__ __align__(16) bf16_t Bxs[128*32];
  const int K = W_;
  int tid = threadIdx.x, wave = tid>>6, lane = tid&63;
  int wm = wave>>1, wn = wave&1, q = lane>>4, ml = lane&15;
  int bm = blockIdx.x, j = blockIdx.y;         // j in 0..7
  const bf16_t* Wyp = WyT + (size_t)j*128*K;
  const bf16_t* Wxp = WxT + (size_t)j*128*K;
  f32x4 accY[4][4] = {}, accX[4][4] = {};
  for (int k0 = 0; k0 < K; k0 += 32){
    stage_tile(X + (size_t)bm*128*K + k0, K, As, wave, lane);
    stage_tile(Wyp + k0, K, Bys, wave, lane);
    stage_tile(Wxp + k0, K, Bxs, wave, lane);
    __syncthreads();
    bf16x8 af[4], bvy[4], bvx[4];
    #pragma unroll
    for (int i=0;i<4;i++) af[i]  = *(const bf16x8*)(As  + (wm*64 + i*16 + ml)*32 + q*8);
    #pragma unroll
    for (int i=0;i<4;i++) bvy[i] = *(const bf16x8*)(Bys + (wn*64 + i*16 + ml)*32 + q*8);
    #pragma unroll
    for (int i=0;i<4;i++) bvx[i] = *(const bf16x8*)(Bxs + (wn*64 + i*16 + ml)*32 + q*8);
    #pragma unroll
    for (int i=0;i<4;i++)
      #pragma unroll
      for (int n=0;n<4;n++){
        accY[i][n] = __builtin_amdgcn_mfma_f32_16x16x32_bf16(af[i], bvy[n], accY[i][n], 0,0,0);
        accX[i][n] = __builtin_amdgcn_mfma_f32_16x16x32_bf16(af[i], bvx[n], accX[i][n], 0,0,0);
      }
    __syncthreads();
  }
  size_t mbase = (size_t)bm*128 + wm*64;
  #pragma unroll
  for (int n=0;n<4;n++){
    int col = j*128 + wn*64 + n*16 + ml;
    float bby = by[col];
    float bbx = bx[col];
    #pragma unroll
    for (int i=0;i<4;i++){
      #pragma unroll
      for (int r=0;r<4;r++){
        size_t row = mbase + i*16 + q*4 + r;
        Y [row*L_ + col] = f2bf(gelu_tanh(accY[i][n][r] + bby));
        U0[row*L_ + col] = f2bf(accX[i][n][r] + bbx);
      }
    }
  }
}

// ---- K2: causal depthwise conv (width 4), f32 weights ----
__global__ void __launch_bounds__(256) conv_kernel(
    const bf16_t* __restrict__ U0, const float* __restrict__ conv_w,
    const float* __restrict__ conv_b, const int* __restrict__ segpos,
    bf16_t* __restrict__ U)
{
  size_t gid = (size_t)blockIdx.x*256 + threadIdx.x;   // BT*L/8 threads
  int lg = (int)(gid & (L_/8 - 1));
  size_t bt = gid >> 7;
  int l = lg*8;
  int t = (int)(bt & (T_-1));
  int pos = segpos[bt];
  float acc[8];
  f32x4 cb0 = *(const f32x4*)(conv_b + l);
  f32x4 cb1 = *(const f32x4*)(conv_b + l + 4);
  #pragma unroll
  for (int e=0;e<4;e++){ acc[e] = cb0[e]; acc[4+e] = cb1[e]; }
  #pragma unroll
  for (int s=0; s<TW_; s++){
    if (pos >= s && t >= s){
      bf16x8 uv = *(const bf16x8*)(U0 + (bt - s)*L_ + l);
      f32x4 w0 = *(const f32x4*)(conv_w + (size_t)(TW_-1-s)*L_ + l);
      f32x4 w1 = *(const f32x4*)(conv_w + (size_t)(TW_-1-s)*L_ + l + 4);
      #pragma unroll
      for (int e=0;e<4;e++){ acc[e] += bf2f(uv[e]) * w0[e]; acc[4+e] += bf2f(uv[4+e]) * w1[e]; }
    }
  }
  bf16x8 o;
  #pragma unroll
  for (int e=0;e<8;e++) o[e] = f2bf(acc[e]);
  *(bf16x8*)(U + bt*L_ + l) = o;
}

// ---- K3: per-head gate GEMMs + RG-LRU prep. U-tile kept resident in LDS:
//      each k-chunk staged once into its own quarter of As; epilogue reads
//      uval from LDS (saves a full 128 MB global re-read of U).
__global__ void __launch_bounds__(256,2) gate_kernel(
    const bf16_t* __restrict__ U,
    const bf16_t* __restrict__ igTw, const bf16_t* __restrict__ agTw, // [H][e=128][d=128]
    const float* __restrict__ igb,  const float* __restrict__ agb,    // [H*128]
    const float* __restrict__ a_param, const int* __restrict__ segpos,
    bf16_t* __restrict__ XN, bf16_t* __restrict__ L2A)
{
  __shared__ __align__(16) bf16_t As [4*128*32];   // full 128x128 U-tile, 4 k-chunks
  __shared__ __align__(16) bf16_t Bxs[128*32];
  __shared__ __align__(16) bf16_t Bas[128*32];
  int tid = threadIdx.x, wave = tid>>6, lane = tid&63;
  int wm = wave>>1, wn = wave&1, q = lane>>4, ml = lane&15;
  int bm = blockIdx.x, h = blockIdx.y;
  f32x4 ax[4][4] = {}, aa[4][4] = {};
  #pragma unroll
  for (int kc = 0; kc < 4; ++kc){
    int k0 = kc*32;
    bf16_t* Asc = As + kc*4096;
    stage_tile(U + (size_t)bm*128*L_ + h*D_ + k0, L_, Asc, wave, lane);
    stage_tile(igTw + (size_t)h*D_*D_ + k0, D_, Bxs, wave, lane);
    stage_tile(agTw + (size_t)h*D_*D_ + k0, D_, Bas, wave, lane);
    __syncthreads();
    bf16x8 af[4], bx_[4], ba_[4];
    #pragma unroll
    for (int i=0;i<4;i++) af[i]  = *(const bf16x8*)(Asc + (wm*64 + i*16 + ml)*32 + q*8);
    #pragma unroll
    for (int i=0;i<4;i++) bx_[i] = *(const bf16x8*)(Bxs + (wn*64 + i*16 + ml)*32 + q*8);
    #pragma unroll
    for (int i=0;i<4;i++) ba_[i] = *(const bf16x8*)(Bas + (wn*64 + i*16 + ml)*32 + q*8);
    #pragma unroll
    for (int i=0;i<4;i++)
      #pragma unroll
      for (int n=0;n<4;n++){
        ax[i][n] = __builtin_amdgcn_mfma_f32_16x16x32_bf16(af[i], bx_[n], ax[i][n], 0,0,0);
        aa[i][n] = __builtin_amdgcn_mfma_f32_16x16x32_bf16(af[i], ba_[n], aa[i][n], 0,0,0);
      }
    __syncthreads();
  }
  size_t mbase = (size_t)bm*128 + wm*64;
  #pragma unroll
  for (int n=0;n<4;n++){
    int e = wn*64 + n*16 + ml;
    int l = h*D_ + e;
    int kc = e >> 5, ci = e & 31;
    float bbx = igb[l];
    float bba = agb[l];
    float spa = softplusf_(a_param[l]);   // softplus(a_param) >= 0
    #pragma unroll
    for (int i=0;i<4;i++){
      #pragma unroll
      for (int r=0;r<4;r++){
        int rl = wm*64 + i*16 + q*4 + r;          // local row
        size_t row = mbase + i*16 + q*4 + r;
        int pos = segpos[row];
        float uval = bf2f(As[kc*4096 + rl*32 + ci]);   // LDS-resident U
        float gx = sigmoidf_(ax[i][n][r] + bbx);
        float ga = sigmoidf_(aa[i][n][r] + bba);
        float l2a = -8.0f * ga * spa * 1.4426950408889634f;  // log2(a)
        bool reset = (pos == 0);
        float mult = reset ? 1.0f : sqrtf(fmaxf(0.0f, 1.0f - exp2f(2.0f*l2a)));
        XN [row*L_ + l] = f2bf(uval * gx * mult);
        L2A[row*L_ + l] = f2bf(reset ? -1e30f : l2a);
      }
    }
  }
}

// ---- K4..K6: chunked linear scan h_t = a_t h_{t-1} + xn_t ----
__global__ void __launch_bounds__(256) scan1_kernel(const bf16_t* __restrict__ L2A,
    const bf16_t* __restrict__ XN, float* __restrict__ Aarr, float* __restrict__ Barr)
{
  int l = blockIdx.x*256 + threadIdx.x;
  int c = blockIdx.y, b = blockIdx.z;
  size_t base = ((size_t)b*T_ + (size_t)c*CHUNK_)*L_ + l;
  float suml = 0.0f, brun = 0.0f;
  for (int t = 0; t < CHUNK_; ++t){
    float la = bf2f(L2A[base + (size_t)t*L_]);
    float xv = bf2f(XN [base + (size_t)t*L_]);
    suml += la;
    brun = exp2f(la)*brun + xv;
  }
  size_t ci = ((size_t)b*NCH_ + c)*L_ + l;
  Aarr[ci] = exp2f(suml);
  Barr[ci] = brun;
}

__global__ void __launch_bounds__(256) scan2_kernel(const float* __restrict__ Aarr,
    const float* __restrict__ Barr, float* __restrict__ Carr)
{
  int l = blockIdx.x*256 + threadIdx.x;
  int b = blockIdx.y;
  float h = 0.0f;
  for (int c = 0; c < NCH_; ++c){
    size_t ci = ((size_t)b*NCH_ + c)*L_ + l;
    Carr[ci] = h;
    h = Aarr[ci]*h + Barr[ci];
  }
}

__global__ void __launch_bounds__(256) scan3_kernel(const bf16_t* __restrict__ L2A,
    const bf16_t* __restrict__ XN, const bf16_t* __restrict__ Y,
    const float* __restrict__ Carr, bf16_t* __restrict__ HY)
{
  int l = blockIdx.x*256 + threadIdx.x;
  int c = blockIdx.y, b = blockIdx.z;
  size_t base = ((size_t)b*T_ + (size_t)c*CHUNK_)*L_ + l;
  float h = Carr[((size_t)b*NCH_ + c)*L_ + l];
  for (int t = 0; t < CHUNK_; ++t){
    float la = bf2f(L2A[base + (size_t)t*L_]);
    float xv = bf2f(XN [base + (size_t)t*L_]);
    h = exp2f(la)*h + xv;
    float yv = bf2f(Y[base + (size_t)t*L_]);
    HY[base + (size_t)t*L_] = f2bf(h*yv);
  }
}

// ---- K7: out = HY @ Wout + bout (f32 output). Two 128-col blocks fused. ----
__global__ void __launch_bounds__(256,2) gemm_out_kernel(
    const bf16_t* __restrict__ A_, const bf16_t* __restrict__ WoT, // [N=1024][K=1024]
    const float* __restrict__ bo, float* __restrict__ Out)
{
  __shared__ __align__(16) bf16_t As [128*32];
  __shared__ __align__(16) bf16_t B0s[128*32];
  __shared__ __align__(16) bf16_t B1s[128*32];
  const int K = L_;
  int tid = threadIdx.x, wave = tid>>6, lane = tid&63;
  int wm = wave>>1, wn = wave&1, q = lane>>4, ml = lane&15;
  int bm = blockIdx.x, j = blockIdx.y;         // j in 0..3
  const bf16_t* W0 = WoT + (size_t)(j*2+0)*128*K;
  const bf16_t* W1 = WoT + (size_t)(j*2+1)*128*K;
  f32x4 acc0[4][4] = {}, acc1[4][4] = {};
  for (int k0 = 0; k0 < K; k0 += 32){
    stage_tile(A_ + (size_t)bm*128*K + k0, K, As, wave, lane);
    stage_tile(W0 + k0, K, B0s, wave, lane);
    stage_tile(W1 + k0, K, B1s, wave, lane);
    __syncthreads();
    bf16x8 af[4], b0[4], b1[4];
    #pragma unroll
    for (int i=0;i<4;i++) af[i] = *(const bf16x8*)(As  + (wm*64 + i*16 + ml)*32 + q*8);
    #pragma unroll
    for (int i=0;i<4;i++) b0[i] = *(const bf16x8*)(B0s + (wn*64 + i*16 + ml)*32 + q*8);
    #pragma unroll
    for (int i=0;i<4;i++) b1[i] = *(const bf16x8*)(B1s + (wn*64 + i*16 + ml)*32 + q*8);
    #pragma unroll
    for (int i=0;i<4;i++)
      #pragma unroll
      for (int n=0;n<4;n++){
        acc0[i][n] = __builtin_amdgcn_mfma_f32_16x16x32_bf16(af[i], b0[n], acc0[i][n], 0,0,0);
        acc1[i][n] = __builtin_amdgcn_mfma_f32_16x16x32_bf16(af[i], b1[n], acc1[i][n], 0,0,0);
      }
    __syncthreads();
  }
  size_t mbase = (size_t)bm*128 + wm*64;
  #pragma unroll
  for (int n=0;n<4;n++){
    int col0 = (j*2+0)*128 + wn*64 + n*16 + ml;
    int col1 = (j*2+1)*128 + wn*64 + n*16 + ml;
    float bb0 = bo[col0];
    float bb1 = bo[col1];
    #pragma unroll
    for (int i=0;i<4;i++){
      #pragma unroll
      for (int r=0;r<4;r++){
        size_t row = mbase + i*16 + q*4 + r;
        Out[row*W_ + col0] = acc0[i][n][r] + bb0;
        Out[row*W_ + col1] = acc1[i][n][r] + bb1;
      }
    }
  }
}

extern "C" void kernel_launch(void* const* d_in, const int* in_sizes, int n_in,
                              void* d_out, int out_size, void* d_ws, size_t ws_size,
                              hipStream_t stream)
{
  (void)in_sizes; (void)n_in; (void)out_size;
  const float* x      = (const float*)d_in[0];
  const int*   segpos = (const int*)  d_in[1];
  const float* Wy     = (const float*)d_in[2];
  const float* by     = (const float*)d_in[3];
  const float* Wx     = (const float*)d_in[4];
  const float* bx     = (const float*)d_in[5];
  const float* conv_w = (const float*)d_in[6];
  const float* conv_b = (const float*)d_in[7];
  const float* a_par  = (const float*)d_in[8];
  const float* igw    = (const float*)d_in[9];
  const float* igb    = (const float*)d_in[10];
  const float* agw    = (const float*)d_in[11];
  const float* agb    = (const float*)d_in[12];
  const float* Wout   = (const float*)d_in[13];
  const float* bout   = (const float*)d_in[14];
  float* out = (float*)d_out;

  char* ws = (char*)d_ws;
  size_t off = 0;
  auto alloc = [&](size_t bytes)->void*{ void* p = ws + off; off += (bytes + 255) & ~(size_t)255; return p; };
  bf16_t* Xbf  = (bf16_t*)alloc((size_t)BT_*W_*2);      // x in bf16; dead after gemm_xw
  bf16_t* WyT  = (bf16_t*)alloc((size_t)W_*L_*2);
  bf16_t* WxT  = (bf16_t*)alloc((size_t)W_*L_*2);
  bf16_t* WoT  = (bf16_t*)alloc((size_t)L_*W_*2);
  bf16_t* igTw = (bf16_t*)alloc((size_t)H_*D_*D_*2);
  bf16_t* agTw = (bf16_t*)alloc((size_t)H_*D_*D_*2);
  bf16_t* Y    = (bf16_t*)alloc((size_t)BT_*L_*2);
  bf16_t* U0   = (bf16_t*)alloc((size_t)BT_*L_*2);      // reused as HY after scan3
  bf16_t* U    = (bf16_t*)alloc((size_t)BT_*L_*2);      // reused as XN by gate epilogue
  float*  Aarr = (float*) alloc((size_t)B_*NCH_*L_*4);
  float*  Barr = (float*) alloc((size_t)B_*NCH_*L_*4);
  float*  Carr = (float*) alloc((size_t)B_*NCH_*L_*4);
  if (ws_size < off) return;  // insufficient workspace: output stays zero (diagnosable)

  bf16_t* L2A = Xbf;   // alias: Xbf dead once gemm_xw completes, before gate_kernel
  bf16_t* HY  = U0;
  bf16_t* XN  = U;

  cvt_kernel<<<dim3(BT_*W_/8/256), 256, 0, stream>>>(x, Xbf, BT_*W_/8);

  dim3 tb(32, 8);
  transpose_f2b<<<dim3(32,32,1), tb, 0, stream>>>(Wy,   WyT, 1024, 1024);
  transpose_f2b<<<dim3(32,32,1), tb, 0, stream>>>(Wx,   WxT, 1024, 1024);
  transpose_f2b<<<dim3(32,32,1), tb, 0, stream>>>(Wout, WoT, 1024, 1024);
  transpose_f2b<<<dim3(4,4,H_),  tb, 0, stream>>>(igw,  igTw, 128, 128);
  transpose_f2b<<<dim3(4,4,H_),  tb, 0, stream>>>(agw,  agTw, 128, 128);

  gemm_xw_kernel<<<dim3(BT_/128, 8), 256, 0, stream>>>(Xbf, WyT, WxT, by, bx, Y, U0);
  conv_kernel<<<dim3(BT_*L_/8/256), 256, 0, stream>>>(U0, conv_w, conv_b, segpos, U);
  gate_kernel<<<dim3(BT_/128, H_), 256, 0, stream>>>(U, igTw, agTw, igb, agb, a_par, segpos, XN, L2A);
  scan1_kernel<<<dim3(L_/256, NCH_, B_), 256, 0, stream>>>(L2A, XN, Aarr, Barr);
  scan2_kernel<<<dim3(L_/256, B_), 256, 0, stream>>>(Aarr, Barr, Carr);
  scan3_kernel<<<dim3(L_/256, NCH_, B_), 256, 0, stream>>>(L2A, XN, Y, Carr, HY);
  gemm_out_kernel<<<dim3(BT_/128, 4), 256, 0, stream>>>(HY, WoT, bout, out);
}